// Round 18
// baseline (54.235 us; speedup 1.0000x reference)
//
#include <hip/hip_runtime.h>
#include <hip/hip_bf16.h>
#include <hip/hip_fp16.h>

#define Bn 8
#define Cn 3
#define Tn 32
#define Hn 128
#define Wn 128
#define HWn (Hn * Wn)          // 16384
#define Nn (Tn * HWn)          // 524288 elems per (b,c)
#define EPSn 1e-5f
#define QT 4                   // 4-way t-split in k2 (8 outputs each)
#define SCH 128                // s-chunks per (b,c) in k2 (128 px each)
#define SSW (SCH * QT)         // 512 ss-partials per bc

__device__ __forceinline__ float silu_f(float v) {
    return v * __builtin_amdgcn_rcpf(1.0f + __expf(-v));
}

// ========== K1: spatial 3x3 conv (1->3ch) + SiLU -> y (fp16), 4 px/thread ==========
__global__ __launch_bounds__(256) void k1_spatial(
    const float* __restrict__ x, const float* __restrict__ wsp,
    const float* __restrict__ bsp, __half* __restrict__ y)
{
    const int tid = threadIdx.x;
    const int sub = tid & 31;           // 32 lane-groups of 4 px
    const int bt = blockIdx.x;          // 0..255
    const int b = bt >> 5, t = bt & 31;
    const int row = blockIdx.y * 8 + (tid >> 5);
    const int col = sub * 4;

    float w[27], bb[3];
#pragma unroll
    for (int i = 0; i < 27; ++i) w[i] = wsp[i];
#pragma unroll
    for (int i = 0; i < 3; ++i) bb[i] = bsp[i];

    const float* xsl = x + ((size_t)b * Tn + t) * HWn + (size_t)row * Wn + col;
    const bool upok = row > 0, dnok = row < Hn - 1;
    const float4 z4 = make_float4(0.f, 0.f, 0.f, 0.f);
    float4 xm = upok ? *(const float4*)(xsl - Wn) : z4;
    float4 xc = *(const float4*)(xsl);
    float4 xp = dnok ? *(const float4*)(xsl + Wn) : z4;
    float xv[3][6];
    {
        float lu, rd;
        lu = __shfl_up(xm.w, 1);  rd = __shfl_down(xm.x, 1);
        xv[0][0] = (sub == 0) ? 0.f : lu; xv[0][1] = xm.x; xv[0][2] = xm.y;
        xv[0][3] = xm.z; xv[0][4] = xm.w; xv[0][5] = (sub == 31) ? 0.f : rd;
        lu = __shfl_up(xc.w, 1);  rd = __shfl_down(xc.x, 1);
        xv[1][0] = (sub == 0) ? 0.f : lu; xv[1][1] = xc.x; xv[1][2] = xc.y;
        xv[1][3] = xc.z; xv[1][4] = xc.w; xv[1][5] = (sub == 31) ? 0.f : rd;
        lu = __shfl_up(xp.w, 1);  rd = __shfl_down(xp.x, 1);
        xv[2][0] = (sub == 0) ? 0.f : lu; xv[2][1] = xp.x; xv[2][2] = xp.y;
        xv[2][3] = xp.z; xv[2][4] = xp.w; xv[2][5] = (sub == 31) ? 0.f : rd;
    }
#pragma unroll
    for (int c = 0; c < 3; ++c) {
        float s0 = bb[c], s1 = bb[c], s2 = bb[c], s3 = bb[c];
#pragma unroll
        for (int i = 0; i < 3; ++i) {
#pragma unroll
            for (int j = 0; j < 3; ++j) {
                const float wv = w[c * 9 + i * 3 + j];
                s0 += wv * xv[i][j];
                s1 += wv * xv[i][j + 1];
                s2 += wv * xv[i][j + 2];
                s3 += wv * xv[i][j + 3];
            }
        }
        __half2 o01 = __floats2half2_rn(silu_f(s0), silu_f(s1));
        __half2 o23 = __floats2half2_rn(silu_f(s2), silu_f(s3));
        __half2* dst = (__half2*)(y + ((size_t)(b * 3 + c) * Tn + t) * HWn
                                  + (size_t)row * Wn + col);
        dst[0] = o01; dst[1] = o23;
    }
}

// ========== K2: temporal 7-tap conv (PACKED fp16) from fp16 y + SiLU^2 + analytics ==========
// Ring kept as raw __half2 (no cvt on load, 7 VGPR); conv via 7x __hfma2 (both px in
// one packed op). Double-SiLU + accumulations stay f32. Register-accumulated pt.
template<int QTg>
__device__ __forceinline__ void k2_body(
    const __half* __restrict__ y, const float* __restrict__ wtp,
    const float* __restrict__ btp, const float* __restrict__ wkt,
    const float* __restrict__ wks,
    __half* __restrict__ raw0, __half* __restrict__ raw1,
    float* __restrict__ pt0p, float* __restrict__ pt1p,
    float* __restrict__ ss0p, float* __restrict__ ss1p)
{
    constexpr int O0 = QTg * 8;
    constexpr int O1 = O0 + 8;
    constexpr int SLO = (O0 - 3 < 0) ? 0 : (O0 - 3);
    constexpr int SHI = (O1 + 2 > Tn - 1) ? (Tn - 1) : (O1 + 2);

    const int tid = threadIdx.x, lane = tid & 63, wave = tid >> 6;
    const int sch = blockIdx.x * 4 + wave;   // 0..127
    const int bc  = blockIdx.y;              // 0..23
    const int c = bc % 3;
    const int s0i = sch * 128 + lane * 2;

    __half2 wt_h[7];
#pragma unroll
    for (int i = 0; i < 7; ++i) {
        const float wv = wtp[c * 7 + i];
        wt_h[i] = __floats2half2_rn(wv, wv);
    }
    const float bt_f = btp[c];
    const __half2 bt_h = __floats2half2_rn(bt_f, bt_f);

    const __half* yb = y + (size_t)bc * Nn + s0i;
    const float2 k0v = *(const float2*)(wkt + s0i);
    const float2 k1v = *(const float2*)(wkt + HWn + s0i);

    __half2 ring[7];
    float2 a0 = make_float2(0.f, 0.f), a1 = make_float2(0.f, 0.f);
    float ps = 0.f, pq = 0.f;
    float pt0a[8], pt1a[8];

#pragma unroll
    for (int tt = SLO; tt <= SHI + 3; ++tt) {
        if (tt <= SHI) {
            ring[tt % 7] = *(const __half2*)(yb + (size_t)tt * HWn);
        }
        const int to = tt - 3;
        if (to >= O0 && to < O1) {          // compile-time pruned per unrolled iter
            __half2 acc = bt_h;
#pragma unroll
            for (int k = 0; k < 7; ++k) {
                const int ts = to + k - 3;
                if (ts >= 0 && ts < Tn)     // compile-time
                    acc = __hfma2(wt_h[k], ring[ts % 7], acc);
            }
            const float2 tv = __half22float2(acc);
            const float g0 = silu_f(silu_f(tv.x));
            const float g1 = silu_f(silu_f(tv.y));
            const float wk0 = wks[to];      // uniform scalar loads
            const float wk1 = wks[Tn + to];
            a0.x += wk0 * g0; a0.y += wk0 * g1;
            a1.x += wk1 * g0; a1.y += wk1 * g1;
            ps += g0 + g1;
            pq += g0 * g0 + g1 * g1;
            pt0a[to - O0] = k0v.x * g0 + k0v.y * g1;   // per-lane, reduced at end
            pt1a[to - O0] = k1v.x * g0 + k1v.y * g1;
        }
    }

    // --- end-of-kernel packed cross-lane reduce (f32) ---
#pragma unroll
    for (int i = 0; i < 8; ++i) {
        pt0a[i] += __shfl_xor(pt0a[i], 1, 64);
        pt0a[i] += __shfl_xor(pt0a[i], 2, 64);
        pt0a[i] += __shfl_xor(pt0a[i], 4, 64);
        pt1a[i] += __shfl_xor(pt1a[i], 1, 64);
        pt1a[i] += __shfl_xor(pt1a[i], 2, 64);
        pt1a[i] += __shfl_xor(pt1a[i], 4, 64);
    }
    {
        const int j = lane & 7;
        float r0 = (j == 0) ? pt0a[0] : (j == 1) ? pt0a[1] : (j == 2) ? pt0a[2]
                 : (j == 3) ? pt0a[3] : (j == 4) ? pt0a[4] : (j == 5) ? pt0a[5]
                 : (j == 6) ? pt0a[6] : pt0a[7];
        float r1 = (j == 0) ? pt1a[0] : (j == 1) ? pt1a[1] : (j == 2) ? pt1a[2]
                 : (j == 3) ? pt1a[3] : (j == 4) ? pt1a[4] : (j == 5) ? pt1a[5]
                 : (j == 6) ? pt1a[6] : pt1a[7];
        r0 += __shfl_xor(r0, 8, 64); r0 += __shfl_xor(r0, 16, 64); r0 += __shfl_xor(r0, 32, 64);
        r1 += __shfl_xor(r1, 8, 64); r1 += __shfl_xor(r1, 16, 64); r1 += __shfl_xor(r1, 32, 64);
        if (lane < 8)
            pt0p[((size_t)bc * Tn + O0 + lane) * SCH + sch] = r0;
        else if (lane < 16)
            pt1p[((size_t)bc * Tn + O0 + (lane & 7)) * SCH + sch] = r1;
    }
    {
        float p0 = ps, p1 = pq;
        p0 += __shfl_xor(p0, 1, 64); p0 += __shfl_xor(p0, 2, 64); p0 += __shfl_xor(p0, 4, 64);
        p1 += __shfl_xor(p1, 1, 64); p1 += __shfl_xor(p1, 2, 64); p1 += __shfl_xor(p1, 4, 64);
        float r = (lane & 1) ? p1 : p0;
        r += __shfl_xor(r, 8, 64);
        r += __shfl_xor(r, 16, 64);
        r += __shfl_xor(r, 32, 64);
        if (lane == 0) ss0p[(size_t)bc * SSW + sch * QT + QTg] = r;
        if (lane == 1) ss1p[(size_t)bc * SSW + sch * QT + QTg] = r;
    }
    {
        const size_t off = (size_t)(QTg * 24 + bc) * HWn + s0i;
        *(__half2*)(raw0 + off) = __floats2half2_rn(a0.x, a0.y);
        *(__half2*)(raw1 + off) = __floats2half2_rn(a1.x, a1.y);
    }
}

__global__ __launch_bounds__(256) void k2_temporal(
    const __half* __restrict__ y, const float* __restrict__ wtp,
    const float* __restrict__ btp, const float* __restrict__ wkt,
    const float* __restrict__ wks,
    __half* __restrict__ raw0, __half* __restrict__ raw1,
    float* __restrict__ pt0p, float* __restrict__ pt1p,
    float* __restrict__ ss0p, float* __restrict__ ss1p)
{
    switch (blockIdx.z) {
    case 0: k2_body<0>(y, wtp, btp, wkt, wks, raw0, raw1, pt0p, pt1p, ss0p, ss1p); break;
    case 1: k2_body<1>(y, wtp, btp, wkt, wks, raw0, raw1, pt0p, pt1p, ss0p, ss1p); break;
    case 2: k2_body<2>(y, wtp, btp, wkt, wks, raw0, raw1, pt0p, pt1p, ss0p, ss1p); break;
    default: k2_body<3>(y, wtp, btp, wkt, wks, raw0, raw1, pt0p, pt1p, ss0p, ss1p); break;
    }
}

// ========== K3a: partial reductions + wkt/wks sums + raw quarter pre-sum (fp16) ==========
__global__ __launch_bounds__(256) void k3a_reduce(
    const float* __restrict__ pt0p, const float* __restrict__ pt1p,
    const float* __restrict__ ss0p, const float* __restrict__ ss1p,
    const float* __restrict__ wkt, const float* __restrict__ wks,
    const __half* __restrict__ raw0, const __half* __restrict__ raw1,
    float* __restrict__ kvt0r, float* __restrict__ kvt1r,
    float* __restrict__ ssS, float* __restrict__ ssSS, float* __restrict__ wsum,
    __half* __restrict__ v0s, __half* __restrict__ v1s)
{
    const int blk = blockIdx.x;
    const int tid = threadIdx.x;
    if (blk < Bn * Cn) {
        const int t = tid >> 3, g = tid & 7;
        const float4* p0 = (const float4*)(pt0p + ((size_t)blk * Tn + t) * SCH) + g * 4;
        const float4* p1 = (const float4*)(pt1p + ((size_t)blk * Tn + t) * SCH) + g * 4;
        float4 A0 = p0[0], A1 = p0[1], A2 = p0[2], A3 = p0[3];
        float4 B0 = p1[0], B1 = p1[1], B2 = p1[2], B3 = p1[3];
        float s0 = ((A0.x + A0.y) + (A0.z + A0.w)) + ((A1.x + A1.y) + (A1.z + A1.w))
                 + ((A2.x + A2.y) + (A2.z + A2.w)) + ((A3.x + A3.y) + (A3.z + A3.w));
        float s1 = ((B0.x + B0.y) + (B0.z + B0.w)) + ((B1.x + B1.y) + (B1.z + B1.w))
                 + ((B2.x + B2.y) + (B2.z + B2.w)) + ((B3.x + B3.y) + (B3.z + B3.w));
        s0 += __shfl_xor(s0, 1, 64); s0 += __shfl_xor(s0, 2, 64); s0 += __shfl_xor(s0, 4, 64);
        s1 += __shfl_xor(s1, 1, 64); s1 += __shfl_xor(s1, 2, 64); s1 += __shfl_xor(s1, 4, 64);
        if (g == 0) { kvt0r[blk * Tn + t] = s0; kvt1r[blk * Tn + t] = s1; }
        // ss reduce: SSW=512 floats each array (128 float4)
        const float4* q0 = (const float4*)(ss0p + (size_t)blk * SSW);
        const float4* q1 = (const float4*)(ss1p + (size_t)blk * SSW);
        float a = 0.f, bb = 0.f;
        if (tid < SSW / 4) {
            float4 a4 = q0[tid], b4 = q1[tid];
            a = (a4.x + a4.y) + (a4.z + a4.w);
            bb = (b4.x + b4.y) + (b4.z + b4.w);
        }
        __shared__ float r0[256], r1[256];
        r0[tid] = a; r1[tid] = bb;
        __syncthreads();
        for (int off = 128; off > 0; off >>= 1) {
            if (tid < off) { r0[tid] += r0[tid + off]; r1[tid] += r1[tid + off]; }
            __syncthreads();
        }
        if (tid == 0) { ssS[blk] = r0[0]; ssSS[blk] = r1[0]; }
    } else if (blk == Bn * Cn) {
        const float4* w0 = (const float4*)wkt;
        const float4* w1 = (const float4*)(wkt + HWn);
        float l0 = 0.f, l1 = 0.f;
        for (int i = tid; i < HWn / 4; i += 256) {
            float4 t0 = w0[i], t1 = w1[i];
            l0 += (t0.x + t0.y) + (t0.z + t0.w);
            l1 += (t1.x + t1.y) + (t1.z + t1.w);
        }
        __shared__ float r0[256], r1[256];
        r0[tid] = l0; r1[tid] = l1;
        __syncthreads();
        for (int off = 128; off > 0; off >>= 1) {
            if (tid < off) { r0[tid] += r0[tid + off]; r1[tid] += r1[tid + off]; }
            __syncthreads();
        }
        if (tid == 0) { wsum[0] = r0[0]; wsum[1] = r1[0]; }
        if (tid < 64) {
            float v = wks[tid];
            v += __shfl_xor(v, 1, 64); v += __shfl_xor(v, 2, 64);
            v += __shfl_xor(v, 4, 64); v += __shfl_xor(v, 8, 64);
            v += __shfl_xor(v, 16, 64);
            if (tid == 0) wsum[2] = v;
            if (tid == 32) wsum[3] = v;
        }
    } else {
        // raw quarter pre-sum: 192 blocks = 24 bc x 8 slices of 2048 px (fp16 in/out)
        const int rs = blk - (Bn * Cn + 1);
        const int bc = rs >> 3, sl = rs & 7;
        const size_t idx = (size_t)bc * HWn + sl * 2048 + tid * 8;
        float acc0[8] = {0,0,0,0,0,0,0,0}, acc1[8] = {0,0,0,0,0,0,0,0};
#pragma unroll
        for (int q = 0; q < QT; ++q) {
            float4 h0 = *(const float4*)(raw0 + (size_t)q * 24 * HWn + idx);
            float4 h1 = *(const float4*)(raw1 + (size_t)q * 24 * HWn + idx);
            const __half2* p0 = (const __half2*)&h0;
            const __half2* p1 = (const __half2*)&h1;
#pragma unroll
            for (int j = 0; j < 4; ++j) {
                float2 f0 = __half22float2(p0[j]);
                float2 f1 = __half22float2(p1[j]);
                acc0[j * 2] += f0.x; acc0[j * 2 + 1] += f0.y;
                acc1[j * 2] += f1.x; acc1[j * 2 + 1] += f1.y;
            }
        }
        float4 o0, o1;
        __half2* s0 = (__half2*)&o0; __half2* s1 = (__half2*)&o1;
#pragma unroll
        for (int j = 0; j < 4; ++j) {
            s0[j] = __floats2half2_rn(acc0[j * 2], acc0[j * 2 + 1]);
            s1[j] = __floats2half2_rn(acc1[j * 2], acc1[j * 2 + 1]);
        }
        *(float4*)(v0s + idx) = o0;
        *(float4*)(v1s + idx) = o1;
    }
}

// ========== K6: inline stats + A-softmax + single-sweep online s-softmax + outer ==========
__global__ __launch_bounds__(256) void k6_fused(
    const __half* __restrict__ v0s, const __half* __restrict__ v1s,
    const float* __restrict__ kvt0r, const float* __restrict__ kvt1r,
    const float* __restrict__ ssS, const float* __restrict__ ssSS,
    const float* __restrict__ wsum, const float* __restrict__ mean_w,
    const float* __restrict__ var_w, const float* __restrict__ snw,
    const float* __restrict__ snb, float* __restrict__ out)
{
    const int ch = blockIdx.x;   // 0..15
    const int bc = blockIdx.y;   // 0..23
    const int tid = threadIdx.x, lane = tid & 63, wave = tid >> 6;
    const int b = bc / 3, c = bc % 3;
    const float Nf = (float)Nn;

    float mln = 0.f, tln = 0.f;
#pragma unroll
    for (int cc = 0; cc < 3; ++cc) {
        float S = ssS[b * 3 + cc], SS = ssSS[b * 3 + cc];
        float m = S / Nf;
        float v = (SS - S * m) / (Nf - 1.0f);
        mln += m; tln += v + m * m;
    }
    mln *= (1.0f / 3.0f); tln *= (1.0f / 3.0f);
    const float vln = tln - mln * mln;
    float mbn = 0.f, tbn = 0.f;
#pragma unroll
    for (int bb2 = 0; bb2 < 8; ++bb2) {
        float S = ssS[bb2 * 3 + c], SS = ssSS[bb2 * 3 + c];
        float m = S / Nf;
        float v = (SS - S * m) / (Nf - 1.0f);
        mbn += m; tbn += v + m * m;
    }
    mbn *= 0.125f; tbn *= 0.125f;
    const float vbn = tbn - mbn * mbn;
    const float S_own = ssS[bc], SS_own = ssSS[bc];
    const float mean_in = S_own / Nf;
    const float var_in = (SS_own - S_own * mean_in) / (Nf - 1.0f);
    float mw0, mw1, mw2, vw0, vw1, vw2;
    {
        float m0 = mean_w[0], m1 = mean_w[1], m2 = mean_w[2];
        float mm = fmaxf(m0, fmaxf(m1, m2));
        float e0 = __expf(m0 - mm), e1 = __expf(m1 - mm), e2 = __expf(m2 - mm);
        float inv = 1.0f / (e0 + e1 + e2);
        mw0 = e0 * inv; mw1 = e1 * inv; mw2 = e2 * inv;
    }
    {
        float v0 = var_w[0], v1 = var_w[1], v2 = var_w[2];
        float vm = fmaxf(v0, fmaxf(v1, v2));
        float e0 = __expf(v0 - vm), e1 = __expf(v1 - vm), e2 = __expf(v2 - vm);
        float inv = 1.0f / (e0 + e1 + e2);
        vw0 = e0 * inv; vw1 = e1 * inv; vw2 = e2 * inv;
    }
    const float mean = mw0 * mean_in + mw1 * mln + mw2 * mbn;
    const float var  = vw0 * var_in + vw1 * vln + vw2 * vbn;
    const float sc = snw[c] / sqrtf(var + EPSn);
    const float sf = snb[c] - mean * sc;
    const float c0 = sf * wsum[2], c1 = sf * wsum[3];
    const float Wt0 = wsum[0], Wt1 = wsum[1];

    __shared__ float aSh[Tn];
    if (tid < Tn) {
        float k0 = sc * kvt0r[bc * Tn + tid] + sf * Wt0;
        float k1 = sc * kvt1r[bc * Tn + tid] + sf * Wt1;
        float m = k0;
#pragma unroll
        for (int d = 1; d < 32; d <<= 1) m = fmaxf(m, __shfl_xor(m, d, 64));
        float e = __expf(k0 - m);
        float s = e;
#pragma unroll
        for (int d = 1; d < 32; d <<= 1) s += __shfl_xor(s, d, 64);
        aSh[tid] = sqrtf(e / s) * k1;
    }

    // --- single-sweep online softmax stats over the bc row (fp16 v0s) ---
    const __half* p0a = v0s + (size_t)bc * HWn;
    float m_run = -3.4e38f, s_run = 0.f;
#pragma unroll
    for (int i = 0; i < 8; ++i) {
        const int idx = tid * 8 + i * 2048;         // 8 px per iter
        float4 hv = *(const float4*)(p0a + idx);
        const __half2* hp = (const __half2*)&hv;
        float vals[8];
#pragma unroll
        for (int j = 0; j < 4; ++j) {
            float2 f = __half22float2(hp[j]);
            vals[j * 2] = sc * f.x + c0;
            vals[j * 2 + 1] = sc * f.y + c0;
        }
        float vm = vals[0];
#pragma unroll
        for (int j = 1; j < 8; ++j) vm = fmaxf(vm, vals[j]);
        const float mn = fmaxf(m_run, vm);
        float sl = 0.f;
#pragma unroll
        for (int j = 0; j < 8; ++j) sl += __expf(vals[j] - mn);
        s_run = s_run * __expf(m_run - mn) + sl;
        m_run = mn;
    }
#pragma unroll
    for (int d = 1; d < 64; d <<= 1) {
        const float mo = __shfl_xor(m_run, d, 64);
        const float so = __shfl_xor(s_run, d, 64);
        const float mn = fmaxf(m_run, mo);
        s_run = s_run * __expf(m_run - mn) + so * __expf(mo - mn);
        m_run = mn;
    }
    __shared__ float wm[4], wsv[4];
    if (lane == 0) { wm[wave] = m_run; wsv[wave] = s_run; }
    __syncthreads();
    float M = fmaxf(fmaxf(wm[0], wm[1]), fmaxf(wm[2], wm[3]));
    float Sexp = wsv[0] * __expf(wm[0] - M) + wsv[1] * __expf(wm[1] - M)
               + wsv[2] * __expf(wm[2] - M) + wsv[3] * __expf(wm[3] - M);
    const float invS = __builtin_amdgcn_rcpf(Sexp);

    // --- own 1024-px slice: B then outer product ---
    const int s = ch * 1024 + tid * 4;
    float2 h0 = *(const float2*)(p0a + s);
    float2 h1 = *(const float2*)(v1s + (size_t)bc * HWn + s);
    const __half2* q0 = (const __half2*)&h0;
    const __half2* q1 = (const __half2*)&h1;
    float2 u0l = __half22float2(q0[0]), u0h = __half22float2(q0[1]);
    float2 u1l = __half22float2(q1[0]), u1h = __half22float2(q1[1]);
    float4 Bv;
    Bv.x = sqrtf(__expf(sc * u0l.x + c0 - M) * invS) * (sc * u1l.x + c1);
    Bv.y = sqrtf(__expf(sc * u0l.y + c0 - M) * invS) * (sc * u1l.y + c1);
    Bv.z = sqrtf(__expf(sc * u0h.x + c0 - M) * invS) * (sc * u1h.x + c1);
    Bv.w = sqrtf(__expf(sc * u0h.y + c0 - M) * invS) * (sc * u1h.y + c1);
    float* op = out + (size_t)bc * Nn + s;
#pragma unroll
    for (int t = 0; t < Tn; ++t) {
        const float av = aSh[t];
        float4 o; o.x = av * Bv.x; o.y = av * Bv.y; o.z = av * Bv.z; o.w = av * Bv.w;
        *(float4*)(op + (size_t)t * HWn) = o;
    }
}

extern "C" void kernel_launch(void* const* d_in, const int* in_sizes, int n_in,
                              void* d_out, int out_size, void* d_ws, size_t ws_size,
                              hipStream_t stream) {
    const float* x          = (const float*)d_in[0];
    const float* w_spatial  = (const float*)d_in[1];
    const float* b_spatial  = (const float*)d_in[2];
    const float* w_temporal = (const float*)d_in[3];
    const float* b_temporal = (const float*)d_in[4];
    const float* sn_weight  = (const float*)d_in[5];
    const float* sn_bias    = (const float*)d_in[6];
    const float* mean_weight= (const float*)d_in[7];
    const float* var_weight = (const float*)d_in[8];
    const float* w_kv_s     = (const float*)d_in[9];
    const float* w_kv_t     = (const float*)d_in[10];
    float* out = (float*)d_out;
    float* ws  = (float*)d_ws;

    // ws layout (floats)
    __half* yh   = (__half*)ws;                          // 12.58M halves = 6,291,456 f
    __half* raw0 = (__half*)(ws + 6291456);              // [QT][24][HWn] h = 786432 f
    __half* raw1 = raw0 + (size_t)QT * Bn * Cn * HWn;    // 786432 f
    float* pt0p  = ws + 6291456 + 2 * 786432;            // 98304
    float* pt1p  = pt0p + (size_t)Bn * Cn * Tn * SCH;    // 98304
    float* ss0p  = pt1p + (size_t)Bn * Cn * Tn * SCH;    // 12288
    float* ss1p  = ss0p + (size_t)Bn * Cn * SSW;         // 12288
    __half* v0s  = (__half*)(ss1p + (size_t)Bn * Cn * SSW);  // 24*HWn h = 196608 f
    __half* v1s  = v0s + (size_t)Bn * Cn * HWn;              // 196608 f
    float* kvt0r = (float*)(v1s + (size_t)Bn * Cn * HWn);    // 768
    float* kvt1r = kvt0r + Bn * Cn * Tn;                 // 768
    float* ssS   = kvt1r + Bn * Cn * Tn;                 // 24
    float* ssSS  = ssS + 24;                             // 24
    float* wsum  = ssSS + 24;                            // 4

    k1_spatial<<<dim3(Bn * Tn, Hn / 8), 256, 0, stream>>>(x, w_spatial, b_spatial, yh);
    k2_temporal<<<dim3(SCH / 4, Bn * Cn, QT), 256, 0, stream>>>(yh, w_temporal,
                                                                b_temporal, w_kv_t,
                                                                w_kv_s, raw0, raw1,
                                                                pt0p, pt1p, ss0p, ss1p);
    k3a_reduce<<<Bn * Cn + 1 + 192, 256, 0, stream>>>(pt0p, pt1p, ss0p, ss1p,
                                                      w_kv_t, w_kv_s, raw0, raw1,
                                                      kvt0r, kvt1r, ssS, ssSS, wsum,
                                                      v0s, v1s);
    k6_fused<<<dim3(16, Bn * Cn), 256, 0, stream>>>(v0s, v1s, kvt0r, kvt1r,
                                                    ssS, ssSS, wsum, mean_weight,
                                                    var_weight, sn_weight, sn_bias, out);
}